// Round 3
// baseline (372.331 us; speedup 1.0000x reference)
//
#include <hip/hip_runtime.h>

// ---------------------------------------------------------------------------
// ElementwiseTensorProducts: fused bf16-MFMA kernel, persistent-WG version.
// B=16,N=4096 -> 65536 tokens = 4096 tiles of 16 tokens.
// Grid = 512 WGs x 256 thr, 8 tiles per WG. Weights held in registers
// (loaded+converted once per WG). Next-tile inputs prefetched into registers
// during current-tile compute (T14 async-stage split).
// Per tile: stage LDS -> proj MFMAs -> elementwise -> output MFMAs -> store.
// ---------------------------------------------------------------------------

typedef float  f32x4  __attribute__((ext_vector_type(4)));
typedef __bf16 bf16x8 __attribute__((ext_vector_type(8)));

#define TOK 16
// LDS byte layout (per WG):
// region1 [0,22528): Ain 64 rows x 256B (staging+proj phases);
//                    then P0 16x256B @0, P1 48x384B @4096 (elementwise+out phases)
// region2 [22528,38912): proj bf16 buffers (z0l,z0r,z1l,z1r)
#define P1_BASE 4096
#define PRJ_Z0L 22528
#define PRJ_Z0R 24576
#define PRJ_Z1L 26624
#define PRJ_Z1R 32768
#define LDS_BYTES 38912

__device__ __forceinline__ unsigned packbf(float lo, float hi) {
    unsigned a = (unsigned)__builtin_bit_cast(unsigned short, (__bf16)lo);
    unsigned b = (unsigned)__builtin_bit_cast(unsigned short, (__bf16)hi);
    return a | (b << 16);
}
__device__ __forceinline__ float bflo(unsigned u) { return __builtin_bit_cast(float, u << 16); }
__device__ __forceinline__ float bfhi(unsigned u) { return __builtin_bit_cast(float, u & 0xffff0000u); }
__device__ __forceinline__ void st_bf(void* p, float v) {
    *(unsigned short*)p = __builtin_bit_cast(unsigned short, (__bf16)v);
}
__device__ __forceinline__ bf16x8 cvtW(const float* p) {
    float4 a = *(const float4*)p;
    float4 b = *(const float4*)(p + 4);
    bf16x8 r;
    r[0] = (__bf16)a.x; r[1] = (__bf16)a.y; r[2] = (__bf16)a.z; r[3] = (__bf16)a.w;
    r[4] = (__bf16)b.x; r[5] = (__bf16)b.y; r[6] = (__bf16)b.z; r[7] = (__bf16)b.w;
    return r;
}
__device__ __forceinline__ f32x4 mm(bf16x8 a, bf16x8 b, f32x4 c) {
    return __builtin_amdgcn_mfma_f32_16x16x32_bf16(a, b, c, 0, 0, 0);
}

__global__ __launch_bounds__(256, 2)
void etp_kernel(const float* __restrict__ z0, const float* __restrict__ z1,
                const float* __restrict__ W0l, const float* __restrict__ b0l,
                const float* __restrict__ W0r, const float* __restrict__ b0r,
                const float* __restrict__ W1l, const float* __restrict__ W1r,
                const float* __restrict__ W0o, const float* __restrict__ b0o,
                const float* __restrict__ W1o,
                float* __restrict__ out0, float* __restrict__ out1,
                int tpw)
{
    __shared__ __align__(16) unsigned char smem[LDS_BYTES];
    const int tid = threadIdx.x;
    const int l  = tid & 63;
    const int w  = tid >> 6;
    const int lr = l & 15;    // row-in-tile for A, n-row for B, col for C
    const int lg = l >> 4;    // 16-lane group

    // ---------------- once per WG: weights -> bf16 register fragments -------
    bf16x8 bL0[4], bR0[4], bL1[4], bR1[4];     // proj weights, this wave's rank tile
    {
        const int r0 = w * 16;
        #pragma unroll
        for (int k = 0; k < 4; ++k) {
            const int wrow = (r0 + lr) * 128 + k * 32 + lg * 8;
            bL0[k] = cvtW(W0l + wrow);
            bR0[k] = cvtW(W0r + wrow);
            bL1[k] = cvtW(W1l + wrow);
            bR1[k] = cvtW(W1r + wrow);
        }
    }
    bf16x8 bO0[2][4], bO1[2][6];               // output weights, this wave's chan tiles
    #pragma unroll
    for (int nn = 0; nn < 2; ++nn) {
        const int crow = nn * 64 + w * 16 + lr;
        #pragma unroll
        for (int k = 0; k < 4; ++k) bO0[nn][k] = cvtW(W0o + crow * 128 + k * 32 + lg * 8);
        #pragma unroll
        for (int k = 0; k < 6; ++k) bO1[nn][k] = cvtW(W1o + crow * 192 + k * 32 + lg * 8);
    }
    const float bl = b0l[w * 16 + lr];
    const float br = b0r[w * 16 + lr];
    float biasO[2];
    biasO[0] = b0o[w * 16 + lr];
    biasO[1] = b0o[64 + w * 16 + lr];

    const int tile0 = blockIdx.x * tpw;
    float4 pf[8];                               // prefetch regs: 2x z0 + 6x z1

    auto issue = [&](int tile) {
        const float4* z0v = (const float4*)(z0 + (size_t)tile * TOK * 128);
        const float4* z1v = (const float4*)(z1 + (size_t)tile * TOK * 3 * 128);
        pf[0] = z0v[tid];
        pf[1] = z0v[tid + 256];
        #pragma unroll
        for (int i = 0; i < 6; ++i) pf[2 + i] = z1v[tid + i * 256];
    };
    auto write_ain = [&]() {
        #pragma unroll
        for (int it = 0; it < 2; ++it) {
            const int idx = tid + it * 256;     // [0,512)
            const int row = idx >> 5, c4 = idx & 31;
            const float4 v = pf[it];
            *(uint2*)(smem + row * 256 + ((c4 * 8) ^ ((row & 7) << 4))) =
                make_uint2(packbf(v.x, v.y), packbf(v.z, v.w));
        }
        #pragma unroll
        for (int it = 0; it < 6; ++it) {
            const int idx = tid + it * 256;     // [0,1536)
            const int row = 16 + (idx >> 5), c4 = idx & 31;
            const float4 v = pf[2 + it];
            *(uint2*)(smem + row * 256 + ((c4 * 8) ^ ((row & 7) << 4))) =
                make_uint2(packbf(v.x, v.y), packbf(v.z, v.w));
        }
    };

    // prologue: stage tile0, issue tile1
    issue(tile0);
    write_ain();
    if (tpw > 1) issue(tile0 + 1);
    __syncthreads();

    for (int t = 0; t < tpw; ++t) {
        const int m0 = (tile0 + t) * TOK;

        // ---------------- phase 2: projections ------------------------------
        {
            f32x4 zero = {0.f, 0.f, 0.f, 0.f};
            f32x4 accL0 = zero, accR0 = zero;
            f32x4 accL1[3], accR1[3];
            #pragma unroll
            for (int mt = 0; mt < 3; ++mt) { accL1[mt] = zero; accR1[mt] = zero; }

            { // z0 rows 0..15
                bf16x8 a[4];
                #pragma unroll
                for (int k = 0; k < 4; ++k)
                    a[k] = *(const bf16x8*)(smem + lr * 256 + ((k * 64 + lg * 16) ^ ((lr & 7) << 4)));
                #pragma unroll
                for (int k = 0; k < 4; ++k) {
                    accL0 = mm(a[k], bL0[k], accL0);
                    accR0 = mm(a[k], bR0[k], accR0);
                }
            }
            #pragma unroll
            for (int mt = 0; mt < 3; ++mt) { // z1 rows 16..63
                const int arow = 16 + mt * 16 + lr;
                bf16x8 a[4];
                #pragma unroll
                for (int k = 0; k < 4; ++k)
                    a[k] = *(const bf16x8*)(smem + arow * 256 + ((k * 64 + lg * 16) ^ ((arow & 7) << 4)));
                #pragma unroll
                for (int k = 0; k < 4; ++k) {
                    accL1[mt] = mm(a[k], bL1[k], accL1[mt]);
                    accR1[mt] = mm(a[k], bR1[k], accR1[mt]);
                }
            }
            // write projections (bf16); biases on the z0 pair
            const int cb = (w * 16 + lr) * 2;
            #pragma unroll
            for (int j = 0; j < 4; ++j) {
                const int trow = lg * 4 + j, sw = (trow & 7) << 4;
                st_bf(smem + PRJ_Z0L + trow * 128 + (cb ^ sw), accL0[j] + bl);
                st_bf(smem + PRJ_Z0R + trow * 128 + (cb ^ sw), accR0[j] + br);
            }
            #pragma unroll
            for (int mt = 0; mt < 3; ++mt)
                #pragma unroll
                for (int j = 0; j < 4; ++j) {
                    const int zr = mt * 16 + lg * 4 + j, sw = (zr & 7) << 4;
                    st_bf(smem + PRJ_Z1L + zr * 128 + (cb ^ sw), accL1[mt][j]);
                    st_bf(smem + PRJ_Z1R + zr * 128 + (cb ^ sw), accR1[mt][j]);
                }
        }
        __syncthreads();   // proj ready; Ain region dead -> safe to write P

        // ---------------- phase 3: elementwise products -> P0/P1 ------------
        {
            #pragma unroll
            for (int it = 0; it < 2; ++it) {            // P0: 16 rows x 32 col-pairs
                const int e = tid + it * 256;
                const int tk = e >> 5, cb4 = (e & 31) * 4;
                const int swt = (tk & 7) << 4;
                unsigned ul = *(const unsigned*)(smem + PRJ_Z0L + tk * 128 + (cb4 ^ swt));
                unsigned ur = *(const unsigned*)(smem + PRJ_Z0R + tk * 128 + (cb4 ^ swt));
                float p0 = bflo(ul) * bflo(ur), p1 = bfhi(ul) * bfhi(ur);
                float s0 = 0.f, s1 = 0.f;
                #pragma unroll
                for (int i = 0; i < 3; ++i) {
                    const int zr = 3 * tk + i, sw = (zr & 7) << 4;
                    unsigned al = *(const unsigned*)(smem + PRJ_Z1L + zr * 128 + (cb4 ^ sw));
                    unsigned ar = *(const unsigned*)(smem + PRJ_Z1R + zr * 128 + (cb4 ^ sw));
                    s0 += bflo(al) * bflo(ar);
                    s1 += bfhi(al) * bfhi(ar);
                }
                *(unsigned*)(smem + tk * 256 + (cb4 ^ swt))         = packbf(p0, p1);
                *(unsigned*)(smem + tk * 256 + ((128 + cb4) ^ swt)) = packbf(s0, s1);
            }
            #pragma unroll
            for (int it = 0; it < 6; ++it) {            // P1: 48 rows x 32 col-pairs
                const int e = tid + it * 256;
                const int row = e >> 5, cb4 = (e & 31) * 4;
                const int tk = row / 3, i = row - 3 * tk;
                const int i1 = (i == 2) ? 0 : i + 1;
                const int i2 = (i == 0) ? 2 : i - 1;
                const int swr = (row & 7) << 4, swt = (tk & 7) << 4;
                unsigned u1l = *(const unsigned*)(smem + PRJ_Z1L + row * 128 + (cb4 ^ swr));
                unsigned u1r = *(const unsigned*)(smem + PRJ_Z1R + row * 128 + (cb4 ^ swr));
                unsigned u0l = *(const unsigned*)(smem + PRJ_Z0L + tk * 128 + (cb4 ^ swt));
                unsigned u0r = *(const unsigned*)(smem + PRJ_Z0R + tk * 128 + (cb4 ^ swt));
                const int ra = 3 * tk + i1, rb = 3 * tk + i2;
                unsigned la  = *(const unsigned*)(smem + PRJ_Z1L + ra * 128 + (cb4 ^ ((ra & 7) << 4)));
                unsigned rbv = *(const unsigned*)(smem + PRJ_Z1R + rb * 128 + (cb4 ^ ((rb & 7) << 4)));
                unsigned lb  = *(const unsigned*)(smem + PRJ_Z1L + rb * 128 + (cb4 ^ ((rb & 7) << 4)));
                unsigned rav = *(const unsigned*)(smem + PRJ_Z1R + ra * 128 + (cb4 ^ ((ra & 7) << 4)));
                float q01_0 = bflo(u0l) * bflo(u1r), q01_1 = bfhi(u0l) * bfhi(u1r);
                float q10_0 = bflo(u1l) * bflo(u0r), q10_1 = bfhi(u1l) * bfhi(u0r);
                float q11_0 = bflo(la) * bflo(rbv) - bflo(lb) * bflo(rav);
                float q11_1 = bfhi(la) * bfhi(rbv) - bfhi(lb) * bfhi(rav);
                unsigned char* base = smem + P1_BASE + row * 384;
                *(unsigned*)(base + (cb4 ^ swr))         = packbf(q01_0, q01_1);
                *(unsigned*)(base + ((128 + cb4) ^ swr)) = packbf(q10_0, q10_1);
                *(unsigned*)(base + ((256 + cb4) ^ swr)) = packbf(q11_0, q11_1);
            }
        }
        __syncthreads();

        // ---------------- phase 4: output GEMMs + store ----------------------
        {
            f32x4 zero = {0.f, 0.f, 0.f, 0.f};
            f32x4 o0[2]; f32x4 o1[2][3];
            #pragma unroll
            for (int nn = 0; nn < 2; ++nn) {
                o0[nn] = zero;
                #pragma unroll
                for (int mt = 0; mt < 3; ++mt) o1[nn][mt] = zero;
            }
            { // out0 from P0
                bf16x8 a[4];
                #pragma unroll
                for (int k = 0; k < 4; ++k)
                    a[k] = *(const bf16x8*)(smem + lr * 256 + ((k * 64 + lg * 16) ^ ((lr & 7) << 4)));
                #pragma unroll
                for (int nn = 0; nn < 2; ++nn)
                    #pragma unroll
                    for (int k = 0; k < 4; ++k) o0[nn] = mm(a[k], bO0[nn][k], o0[nn]);
            }
            #pragma unroll
            for (int mt = 0; mt < 3; ++mt) { // out1 from P1
                const int arow = mt * 16 + lr;
                bf16x8 a[6];
                #pragma unroll
                for (int k = 0; k < 6; ++k)
                    a[k] = *(const bf16x8*)(smem + P1_BASE + arow * 384 + ((k * 64 + lg * 16) ^ ((arow & 7) << 4)));
                #pragma unroll
                for (int nn = 0; nn < 2; ++nn)
                    #pragma unroll
                    for (int k = 0; k < 6; ++k) o1[nn][mt] = mm(a[k], bO1[nn][k], o1[nn][mt]);
            }
            // stores
            #pragma unroll
            for (int nn = 0; nn < 2; ++nn) {
                const int c = nn * 64 + w * 16 + lr;
                #pragma unroll
                for (int j = 0; j < 4; ++j) {
                    const int tk = lg * 4 + j;
                    out0[(size_t)(m0 + tk) * 128 + c] = o0[nn][j] + biasO[nn];
                }
                #pragma unroll
                for (int mt = 0; mt < 3; ++mt)
                    #pragma unroll
                    for (int j = 0; j < 4; ++j) {
                        const int zr = mt * 16 + lg * 4 + j;
                        out1[((size_t)m0 * 3 + zr) * 128 + c] = o1[nn][mt][j];
                    }
            }
        }
        __syncthreads();   // P reads done; Ain region free for next tile

        if (t + 1 < tpw) {
            write_ain();                       // stage tile t+1 (regs -> LDS)
            if (t + 2 < tpw) issue(tile0 + t + 2);
            __syncthreads();
        }
    }
}

extern "C" void kernel_launch(void* const* d_in, const int* in_sizes, int n_in,
                              void* d_out, int out_size, void* d_ws, size_t ws_size,
                              hipStream_t stream)
{
    const float* z0  = (const float*)d_in[0];
    const float* z1  = (const float*)d_in[1];
    const float* W0l = (const float*)d_in[2];
    const float* b0l = (const float*)d_in[3];
    const float* W0r = (const float*)d_in[4];
    const float* b0r = (const float*)d_in[5];
    const float* W1l = (const float*)d_in[6];
    const float* W1r = (const float*)d_in[7];
    const float* W0o = (const float*)d_in[8];
    const float* b0o = (const float*)d_in[9];
    const float* W1o = (const float*)d_in[10];

    const int tokens = in_sizes[0] / 128;        // 65536
    const int ntiles = tokens / TOK;             // 4096
    int grid = 512;
    if (grid > ntiles) grid = ntiles;
    const int tpw = ntiles / grid;               // 8

    float* out0 = (float*)d_out;
    float* out1 = out0 + (size_t)tokens * 128;

    hipLaunchKernelGGL(etp_kernel, dim3(grid), dim3(256), 0, stream,
                       z0, z1, W0l, b0l, W0r, b0r, W1l, W1r, W0o, b0o, W1o,
                       out0, out1, tpw);
}

// Round 4
// 265.535 us; speedup vs baseline: 1.4022x; 1.4022x over previous
//
#include <hip/hip_runtime.h>

// ---------------------------------------------------------------------------
// ElementwiseTensorProducts: fused bf16-MFMA kernel.
// Non-persistent (R1 structure): 4096 WGs x 256 thr, one 16-token tile each.
// NEW: weights pre-converted once per launch by etp_setup into bf16 MFMA
// fragments in d_ws, laid out [role][k][wave][lane] so the main kernel loads
// each fragment as one coalesced dwordx4 (no cvt VALU, no redundant loads).
// Register pressure stays phased: proj frags (64 VGPR) die before phase 4;
// output frags loaded per-nn (<=40 live). launch_bounds(256,3) -> no spill.
// ---------------------------------------------------------------------------

typedef float  f32x4  __attribute__((ext_vector_type(4)));
typedef __bf16 bf16x8 __attribute__((ext_vector_type(8)));

#define TOK 16
// LDS byte layout (per WG):
// region1 [0,22528): Ain 64 rows x 256B (staging+proj phases);
//                    then P0 16x256B @0, P1 48x384B @4096 (elementwise+out)
// region2 [22528,38912): proj bf16 buffers (z0l,z0r,z1l,z1r)
#define P1_BASE 4096
#define PRJ_Z0L 22528
#define PRJ_Z0R 24576
#define PRJ_Z1L 26624
#define PRJ_Z1R 32768
#define LDS_BYTES 38912

// weight-fragment workspace: A(proj) 4096 + B0 2048 + B1 3072 frags, 16B each
#define FRAG_A  0
#define FRAG_B0 4096
#define FRAG_B1 6144
#define NFRAG   9216
#define WS_NEED (NFRAG * 16)

__device__ __forceinline__ unsigned packbf(float lo, float hi) {
    unsigned a = (unsigned)__builtin_bit_cast(unsigned short, (__bf16)lo);
    unsigned b = (unsigned)__builtin_bit_cast(unsigned short, (__bf16)hi);
    return a | (b << 16);
}
__device__ __forceinline__ float bflo(unsigned u) { return __builtin_bit_cast(float, u << 16); }
__device__ __forceinline__ float bfhi(unsigned u) { return __builtin_bit_cast(float, u & 0xffff0000u); }
__device__ __forceinline__ void st_bf(void* p, float v) {
    *(unsigned short*)p = __builtin_bit_cast(unsigned short, (__bf16)v);
}
__device__ __forceinline__ bf16x8 cvtW(const float* p) {
    float4 a = *(const float4*)p;
    float4 b = *(const float4*)(p + 4);
    bf16x8 r;
    r[0] = (__bf16)a.x; r[1] = (__bf16)a.y; r[2] = (__bf16)a.z; r[3] = (__bf16)a.w;
    r[4] = (__bf16)b.x; r[5] = (__bf16)b.y; r[6] = (__bf16)b.z; r[7] = (__bf16)b.w;
    return r;
}
__device__ __forceinline__ f32x4 mm(bf16x8 a, bf16x8 b, f32x4 c) {
    return __builtin_amdgcn_mfma_f32_16x16x32_bf16(a, b, c, 0, 0, 0);
}

// ---------------- setup: fp32 weights -> bf16 fragment buffer ---------------
__global__ void etp_setup(const float* __restrict__ W0l, const float* __restrict__ W0r,
                          const float* __restrict__ W1l, const float* __restrict__ W1r,
                          const float* __restrict__ W0o, const float* __restrict__ W1o,
                          bf16x8* __restrict__ wsf)
{
    const int fid = blockIdx.x * 256 + threadIdx.x;
    if (fid >= NFRAG) return;
    const int l = fid & 63, lr = l & 15, lg = l >> 4;
    const float* src;
    if (fid < FRAG_B0) {                 // proj frags: fid = ((mat*4+k)*4+w)*64+l
        const int w = (fid >> 6) & 3, k = (fid >> 8) & 3, mat = fid >> 10;
        const float* Wm = (mat == 0) ? W0l : (mat == 1) ? W0r : (mat == 2) ? W1l : W1r;
        src = Wm + (w * 16 + lr) * 128 + k * 32 + lg * 8;
    } else if (fid < FRAG_B1) {          // W0o frags: ((nn*4+k)*4+w)*64+l
        const int f = fid - FRAG_B0;
        const int w = (f >> 6) & 3, k = (f >> 8) & 3, nn = f >> 10;
        src = W0o + (nn * 64 + w * 16 + lr) * 128 + k * 32 + lg * 8;
    } else {                             // W1o frags: ((nn*6+k)*4+w)*64+l
        const int f = fid - FRAG_B1;
        const int w = (f >> 6) & 3, nk = f >> 8;
        const int nn = nk / 6, k = nk - 6 * nn;
        src = W1o + (nn * 64 + w * 16 + lr) * 192 + k * 32 + lg * 8;
    }
    wsf[fid] = cvtW(src);
}

// ---------------- main fused kernel -----------------------------------------
template <bool WS>
__global__ __launch_bounds__(256, 3)
void etp_kernel(const float* __restrict__ z0, const float* __restrict__ z1,
                const float* __restrict__ W0l, const float* __restrict__ b0l,
                const float* __restrict__ W0r, const float* __restrict__ b0r,
                const float* __restrict__ W1l, const float* __restrict__ W1r,
                const float* __restrict__ W0o, const float* __restrict__ b0o,
                const float* __restrict__ W1o,
                const bf16x8* __restrict__ wsf,
                float* __restrict__ out0, float* __restrict__ out1)
{
    __shared__ __align__(16) unsigned char smem[LDS_BYTES];
    const int tid = threadIdx.x;
    const int m0  = blockIdx.x * TOK;
    const int l  = tid & 63;
    const int w  = tid >> 6;
    const int lr = l & 15;    // row-in-tile for A, n-row for B, col for C
    const int lg = l >> 4;    // 16-lane group

    // issue proj weight-fragment loads FIRST (L2-resident; latency hides
    // under the input staging below)
    bf16x8 bL0[4], bR0[4], bL1[4], bR1[4];
    if constexpr (WS) {
        #pragma unroll
        for (int k = 0; k < 4; ++k) {
            bL0[k] = wsf[FRAG_A + ((0 * 4 + k) * 4 + w) * 64 + l];
            bR0[k] = wsf[FRAG_A + ((1 * 4 + k) * 4 + w) * 64 + l];
            bL1[k] = wsf[FRAG_A + ((2 * 4 + k) * 4 + w) * 64 + l];
            bR1[k] = wsf[FRAG_A + ((3 * 4 + k) * 4 + w) * 64 + l];
        }
    } else {
        #pragma unroll
        for (int k = 0; k < 4; ++k) {
            const int wrow = (w * 16 + lr) * 128 + k * 32 + lg * 8;
            bL0[k] = cvtW(W0l + wrow);
            bR0[k] = cvtW(W0r + wrow);
            bL1[k] = cvtW(W1l + wrow);
            bR1[k] = cvtW(W1r + wrow);
        }
    }
    const float bl = b0l[w * 16 + lr];
    const float br = b0r[w * 16 + lr];

    // ---------------- phase 1: stage inputs to LDS as bf16 (swizzled) -------
    {
        const float4* z0v = (const float4*)(z0 + (size_t)m0 * 128);       // 16 rows x 32 f4
        const float4* z1v = (const float4*)(z1 + (size_t)m0 * 3 * 128);   // 48 rows x 32 f4
        #pragma unroll
        for (int it = 0; it < 2; ++it) {
            int idx = tid + it * 256;               // [0,512)
            int row = idx >> 5, c4 = idx & 31;
            float4 v = z0v[idx];
            *(uint2*)(smem + row * 256 + ((c4 * 8) ^ ((row & 7) << 4))) =
                make_uint2(packbf(v.x, v.y), packbf(v.z, v.w));
        }
        #pragma unroll
        for (int it = 0; it < 6; ++it) {
            int idx = tid + it * 256;               // [0,1536)
            int row = 16 + (idx >> 5), c4 = idx & 31;
            float4 v = z1v[idx];
            *(uint2*)(smem + row * 256 + ((c4 * 8) ^ ((row & 7) << 4))) =
                make_uint2(packbf(v.x, v.y), packbf(v.z, v.w));
        }
    }
    __syncthreads();

    // ---------------- phase 2: projections ----------------------------------
    {
        f32x4 zero = {0.f, 0.f, 0.f, 0.f};
        f32x4 accL0 = zero, accR0 = zero;
        f32x4 accL1[3], accR1[3];
        #pragma unroll
        for (int mt = 0; mt < 3; ++mt) { accL1[mt] = zero; accR1[mt] = zero; }

        { // z0 rows 0..15
            bf16x8 a[4];
            #pragma unroll
            for (int k = 0; k < 4; ++k)
                a[k] = *(const bf16x8*)(smem + lr * 256 + ((k * 64 + lg * 16) ^ ((lr & 7) << 4)));
            #pragma unroll
            for (int k = 0; k < 4; ++k) {
                accL0 = mm(a[k], bL0[k], accL0);
                accR0 = mm(a[k], bR0[k], accR0);
            }
        }
        #pragma unroll
        for (int mt = 0; mt < 3; ++mt) { // z1 rows 16..63
            const int arow = 16 + mt * 16 + lr;
            bf16x8 a[4];
            #pragma unroll
            for (int k = 0; k < 4; ++k)
                a[k] = *(const bf16x8*)(smem + arow * 256 + ((k * 64 + lg * 16) ^ ((arow & 7) << 4)));
            #pragma unroll
            for (int k = 0; k < 4; ++k) {
                accL1[mt] = mm(a[k], bL1[k], accL1[mt]);
                accR1[mt] = mm(a[k], bR1[k], accR1[mt]);
            }
        }
        // write projections (bf16) + biases for the z0 pair
        const int cb = (w * 16 + lr) * 2;
        #pragma unroll
        for (int j = 0; j < 4; ++j) {
            const int trow = lg * 4 + j, sw = (trow & 7) << 4;
            st_bf(smem + PRJ_Z0L + trow * 128 + (cb ^ sw), accL0[j] + bl);
            st_bf(smem + PRJ_Z0R + trow * 128 + (cb ^ sw), accR0[j] + br);
        }
        #pragma unroll
        for (int mt = 0; mt < 3; ++mt)
            #pragma unroll
            for (int j = 0; j < 4; ++j) {
                const int zr = mt * 16 + lg * 4 + j, sw = (zr & 7) << 4;
                st_bf(smem + PRJ_Z1L + zr * 128 + (cb ^ sw), accL1[mt][j]);
                st_bf(smem + PRJ_Z1R + zr * 128 + (cb ^ sw), accR1[mt][j]);
            }
    }
    __syncthreads();   // proj ready; Ain region now dead -> safe to write P

    // ---------------- phase 3: elementwise products -> P0/P1 ----------------
    {
        #pragma unroll
        for (int it = 0; it < 2; ++it) {            // P0: 16 rows x 32 col-pairs
            const int e = tid + it * 256;
            const int t = e >> 5, cb4 = (e & 31) * 4;
            const int swt = (t & 7) << 4;
            unsigned ul = *(const unsigned*)(smem + PRJ_Z0L + t * 128 + (cb4 ^ swt));
            unsigned ur = *(const unsigned*)(smem + PRJ_Z0R + t * 128 + (cb4 ^ swt));
            float p0 = bflo(ul) * bflo(ur), p1 = bfhi(ul) * bfhi(ur);
            float s0 = 0.f, s1 = 0.f;
            #pragma unroll
            for (int i = 0; i < 3; ++i) {
                const int zr = 3 * t + i, sw = (zr & 7) << 4;
                unsigned al = *(const unsigned*)(smem + PRJ_Z1L + zr * 128 + (cb4 ^ sw));
                unsigned ar = *(const unsigned*)(smem + PRJ_Z1R + zr * 128 + (cb4 ^ sw));
                s0 += bflo(al) * bflo(ar);
                s1 += bfhi(al) * bfhi(ar);
            }
            *(unsigned*)(smem + t * 256 + (cb4 ^ swt))         = packbf(p0, p1);
            *(unsigned*)(smem + t * 256 + ((128 + cb4) ^ swt)) = packbf(s0, s1);
        }
        #pragma unroll
        for (int it = 0; it < 6; ++it) {            // P1: 48 rows x 32 col-pairs
            const int e = tid + it * 256;
            const int row = e >> 5, cb4 = (e & 31) * 4;
            const int t = row / 3, i = row - 3 * t;
            const int i1 = (i == 2) ? 0 : i + 1;
            const int i2 = (i == 0) ? 2 : i - 1;
            const int swr = (row & 7) << 4, swt = (t & 7) << 4;
            unsigned u1l = *(const unsigned*)(smem + PRJ_Z1L + row * 128 + (cb4 ^ swr));
            unsigned u1r = *(const unsigned*)(smem + PRJ_Z1R + row * 128 + (cb4 ^ swr));
            unsigned u0l = *(const unsigned*)(smem + PRJ_Z0L + t * 128 + (cb4 ^ swt));
            unsigned u0r = *(const unsigned*)(smem + PRJ_Z0R + t * 128 + (cb4 ^ swt));
            const int ra = 3 * t + i1, rb = 3 * t + i2;
            unsigned la  = *(const unsigned*)(smem + PRJ_Z1L + ra * 128 + (cb4 ^ ((ra & 7) << 4)));
            unsigned rbv = *(const unsigned*)(smem + PRJ_Z1R + rb * 128 + (cb4 ^ ((rb & 7) << 4)));
            unsigned lb  = *(const unsigned*)(smem + PRJ_Z1L + rb * 128 + (cb4 ^ ((rb & 7) << 4)));
            unsigned rav = *(const unsigned*)(smem + PRJ_Z1R + ra * 128 + (cb4 ^ ((ra & 7) << 4)));
            float q01_0 = bflo(u0l) * bflo(u1r), q01_1 = bfhi(u0l) * bfhi(u1r);
            float q10_0 = bflo(u1l) * bflo(u0r), q10_1 = bfhi(u1l) * bfhi(u0r);
            float q11_0 = bflo(la) * bflo(rbv) - bflo(lb) * bflo(rav);
            float q11_1 = bfhi(la) * bfhi(rbv) - bfhi(lb) * bfhi(rav);
            unsigned char* base = smem + P1_BASE + row * 384;
            *(unsigned*)(base + (cb4 ^ swr))         = packbf(q01_0, q01_1);
            *(unsigned*)(base + ((128 + cb4) ^ swr)) = packbf(q10_0, q10_1);
            *(unsigned*)(base + ((256 + cb4) ^ swr)) = packbf(q11_0, q11_1);
        }
    }
    __syncthreads();

    // ---------------- phase 4: output GEMMs + store --------------------------
    {
        f32x4 zero = {0.f, 0.f, 0.f, 0.f};
        f32x4 o0[2]; f32x4 o1[2][3];
        #pragma unroll
        for (int nn = 0; nn < 2; ++nn) {
            o0[nn] = zero;
            #pragma unroll
            for (int mt = 0; mt < 3; ++mt) o1[nn][mt] = zero;
        }
        bf16x8 a0[4];                                // P0 A-frags (shared by both nn)
        #pragma unroll
        for (int k = 0; k < 4; ++k)
            a0[k] = *(const bf16x8*)(smem + lr * 256 + ((k * 64 + lg * 16) ^ ((lr & 7) << 4)));

        #pragma unroll
        for (int nn = 0; nn < 2; ++nn) {
            bf16x8 c0[4], c1[6];
            if constexpr (WS) {
                #pragma unroll
                for (int k = 0; k < 4; ++k) c0[k] = wsf[FRAG_B0 + ((nn * 4 + k) * 4 + w) * 64 + l];
                #pragma unroll
                for (int k = 0; k < 6; ++k) c1[k] = wsf[FRAG_B1 + ((nn * 6 + k) * 4 + w) * 64 + l];
            } else {
                const int crow = nn * 64 + w * 16 + lr;
                #pragma unroll
                for (int k = 0; k < 4; ++k) c0[k] = cvtW(W0o + crow * 128 + k * 32 + lg * 8);
                #pragma unroll
                for (int k = 0; k < 6; ++k) c1[k] = cvtW(W1o + crow * 192 + k * 32 + lg * 8);
            }
            #pragma unroll
            for (int k = 0; k < 4; ++k) o0[nn] = mm(a0[k], c0[k], o0[nn]);
            #pragma unroll
            for (int mt = 0; mt < 3; ++mt) {
                const int arow = mt * 16 + lr;
                bf16x8 a[6];
                #pragma unroll
                for (int k = 0; k < 6; ++k)
                    a[k] = *(const bf16x8*)(smem + P1_BASE + arow * 384 + ((k * 64 + lg * 16) ^ ((arow & 7) << 4)));
                #pragma unroll
                for (int k = 0; k < 6; ++k) o1[nn][mt] = mm(a[k], c1[k], o1[nn][mt]);
            }
        }
        // stores
        #pragma unroll
        for (int nn = 0; nn < 2; ++nn) {
            const int c = nn * 64 + w * 16 + lr;
            const float bias = b0o[c];
            #pragma unroll
            for (int j = 0; j < 4; ++j) {
                const int t = lg * 4 + j;
                out0[(size_t)(m0 + t) * 128 + c] = o0[nn][j] + bias;
            }
            #pragma unroll
            for (int mt = 0; mt < 3; ++mt)
                #pragma unroll
                for (int j = 0; j < 4; ++j) {
                    const int zr = mt * 16 + lg * 4 + j;
                    out1[((size_t)m0 * 3 + zr) * 128 + c] = o1[nn][mt][j];
                }
        }
    }
}

extern "C" void kernel_launch(void* const* d_in, const int* in_sizes, int n_in,
                              void* d_out, int out_size, void* d_ws, size_t ws_size,
                              hipStream_t stream)
{
    const float* z0  = (const float*)d_in[0];
    const float* z1  = (const float*)d_in[1];
    const float* W0l = (const float*)d_in[2];
    const float* b0l = (const float*)d_in[3];
    const float* W0r = (const float*)d_in[4];
    const float* b0r = (const float*)d_in[5];
    const float* W1l = (const float*)d_in[6];
    const float* W1r = (const float*)d_in[7];
    const float* W0o = (const float*)d_in[8];
    const float* b0o = (const float*)d_in[9];
    const float* W1o = (const float*)d_in[10];

    const int tokens = in_sizes[0] / 128;        // 65536
    float* out0 = (float*)d_out;
    float* out1 = out0 + (size_t)tokens * 128;
    bf16x8* wsf = (bf16x8*)d_ws;

    if (ws_size >= (size_t)WS_NEED) {
        hipLaunchKernelGGL(etp_setup, dim3((NFRAG + 255) / 256), dim3(256), 0, stream,
                           W0l, W0r, W1l, W1r, W0o, W1o, wsf);
        hipLaunchKernelGGL((etp_kernel<true>), dim3(tokens / TOK), dim3(256), 0, stream,
                           z0, z1, W0l, b0l, W0r, b0r, W1l, W1r, W0o, b0o, W1o,
                           wsf, out0, out1);
    } else {
        hipLaunchKernelGGL((etp_kernel<false>), dim3(tokens / TOK), dim3(256), 0, stream,
                           z0, z1, W0l, b0l, W0r, b0r, W1l, W1r, W0o, b0o, W1o,
                           wsf, out0, out1);
    }
}